// Round 7
// baseline (15.455 us; speedup 1.0000x reference)
//
#include <hip/hip_runtime.h>

typedef unsigned int u32;
typedef unsigned long long u64;

// AdderNet conv+ReLU: out[n,o,h,w] = relu(b[o] - sum_{c,kh,kw} |x - w|)
// x:[8,64,128,128] f32, w:[64,64,3,3], b:[64], out:[8,64,128,128] f32.
//
// Triangle-inequality screen over a SUBSET of terms (valid for all inputs):
//   sum_{all} |x_patch - w[o]| >= S'(n,h,w) - Wsum'[o]
// subset = channels 0..15, center input row (kh=1), in-bounds cols:
//   S'       = sum_{dc in {-1,0,1}, in-bounds} A16(n,h,w+dc)
//   A16      = sum_{c<16} |x[n,c,h,w]|
//   Wsum'[o] = sum_{c<16} sum_{kw} |w[o,c,1,kw]|
// If S' >= thr = max_o(Wsum'[o]+b[o]) + 1.0 (fp32 slack), all 64 outputs at
// that pixel are exactly 0. Failing cols are recorded in a per-row 128-bit
// mask (d_ws) and recomputed exactly by K2, so the kernel pair is correct
// for arbitrary inputs; unit-scale margin is ~5-7 sigma -> mask is all-zero.
//
// K1 (one dispatch, role-specialized blocks, parity-interleaved):
//   even bid -> pure 32KB zero-fill burst of out (pure write stream)
//   odd  bid -> screen one image row: read 16 channels (8KB), no out stores
// K2 (8 blocks): read masks; exact fp32 fix-up of failing cols (normally none).
// Traffic: 33.5 MB write + 8.6 MB read ~ 6.7 us floor at 6.3 TB/s.

#define Hh 128
#define Ww 128
#define C_IN 64
#define O_OUT 64
#define NB 8
#define PIX (Hh * Ww)
#define MASK_BYTES ((size_t)NB * Hh * 2 * 8)   // 16384

__global__ __launch_bounds__(256)
void k1_fill_screen(const float* __restrict__ x, const float* __restrict__ w,
                    const float* __restrict__ b, float* __restrict__ out,
                    u64* __restrict__ mask) {
    const int tid = threadIdx.x, bid = blockIdx.x;

    if (!(bid & 1)) {
        // ---- pure zero-fill: 1024 blocks x 2048 float4 = 33.5 MB ----
        const int f = bid >> 1;
        float4* o4 = (float4*)out + (size_t)f * 2048;
        const float4 z = make_float4(0.f, 0.f, 0.f, 0.f);
        #pragma unroll
        for (int j = 0; j < 8; ++j) o4[(j << 8) + tid] = z;
        return;
    }

    // ---- screen one image row ----
    __shared__ float Ap[8 * 128];
    __shared__ float Afin[128];
    __shared__ float wmax[4];

    const int s = bid >> 1;
    const int n = s >> 7, h = s & 127;
    const int c4 = tid & 31;           // float4 col index
    const int g  = tid >> 5;           // covers channels g and g+8 (c < 16)

    const float4* xn = (const float4*)x + (size_t)n * C_IN * (PIX / 4)
                     + (size_t)h * (Ww / 4) + c4;
    const float4 a0 = xn[(size_t)g * (PIX / 4)];
    const float4 a1 = xn[(size_t)(g + 8) * (PIX / 4)];

    // threshold: thr = max_o( sum_{c<16}|w[o,c,1,:]| + b[o] )
    const int o = tid >> 2, jj = tid & 3;      // 64 o x 4 threads (4 ch each)
    float sthr = 0.f;
    #pragma unroll
    for (int k = 0; k < 4; ++k) {
        const float* wp = w + (size_t)o * 576 + (jj * 4 + k) * 9 + 3;  // kh=1
        sthr += fabsf(wp[0]) + fabsf(wp[1]) + fabsf(wp[2]);
    }
    sthr += __shfl_xor(sthr, 1); sthr += __shfl_xor(sthr, 2);
    float v = sthr + b[o];
    #pragma unroll
    for (int d = 4; d < 64; d <<= 1) v = fmaxf(v, __shfl_xor(v, d));
    if ((tid & 63) == 0) wmax[tid >> 6] = v;

    // A16 partials
    float4 a;
    a.x = fabsf(a0.x) + fabsf(a1.x); a.y = fabsf(a0.y) + fabsf(a1.y);
    a.z = fabsf(a0.z) + fabsf(a1.z); a.w = fabsf(a0.w) + fabsf(a1.w);
    *(float4*)&Ap[g * 128 + c4 * 4] = a;
    __syncthreads();

    if (tid < 128) {
        float sum = 0.f;
        #pragma unroll
        for (int gg = 0; gg < 8; ++gg) sum += Ap[gg * 128 + tid];
        Afin[tid] = sum;
    }
    __syncthreads();

    const float thr = fmaxf(fmaxf(wmax[0], wmax[1]),
                            fmaxf(wmax[2], wmax[3])) + 1.0f;

    bool fail = false;
    if (tid < 128) {
        float S = Afin[tid];
        if (tid > 0)   S += Afin[tid - 1];
        if (tid < 127) S += Afin[tid + 1];
        fail = !(S >= thr);            // cannot prove zero
    }
    const u64 m = __ballot(fail);
    if (tid < 128 && (tid & 63) == 0)
        mask[(size_t)(n * Hh + h) * 2 + (tid >> 6)] = m;   // written EVERY call
}

// ---- K2: exact fp32 fix-up of mask-flagged cols (normally all-zero) ----
__global__ __launch_bounds__(256)
void k2_fixup(const float* __restrict__ x, const float* __restrict__ w,
              const float* __restrict__ b, float* __restrict__ out,
              const u64* __restrict__ mask) {
    const int n = blockIdx.x, tid = threadIdx.x;
    const u64 m = mask[(size_t)n * 256 + tid];    // tid = h*2 + colhalf
    if (!m) return;
    const int h = tid >> 1, cbase = (tid & 1) << 6;
    const float* xs = x + (size_t)n * C_IN * PIX;
    u64 mm = m;
    while (mm) {
        const int bit = __ffsll((unsigned long long)mm) - 1;
        mm &= mm - 1;
        const int col = cbase + bit;
        for (int o = 0; o < O_OUT; ++o) {
            const float* wo = w + (size_t)o * C_IN * 9;
            float sum = 0.f;
            for (int c = 0; c < C_IN; ++c) {
                const float* xc = xs + (size_t)c * PIX;
                const float* wc = wo + c * 9;
                #pragma unroll
                for (int kh = 0; kh < 3; ++kh) {
                    const int gh = h + kh - 1;
                    #pragma unroll
                    for (int kw = 0; kw < 3; ++kw) {
                        const int gw = col + kw - 1;
                        const float xval = ((unsigned)gh < (unsigned)Hh &&
                                            (unsigned)gw < (unsigned)Ww)
                                           ? xc[gh * Ww + gw] : 0.f;
                        sum += fabsf(xval - wc[kh * 3 + kw]);
                    }
                }
            }
            out[(size_t)(n * O_OUT + o) * PIX + h * Ww + col] = fmaxf(b[o] - sum, 0.f);
        }
    }
}

// ---- fallback (ws too small): round-6 fused row kernel, no scratch ----
__global__ __launch_bounds__(256)
void adder_row_screen(const float* __restrict__ x, const float* __restrict__ w,
                      const float* __restrict__ b, float* __restrict__ out) {
    __shared__ float Ap[8 * 128];
    __shared__ float Afin[128];
    __shared__ float wmax[4];
    __shared__ u32   nfail;
    __shared__ u32   flist[128];

    const int tid = threadIdx.x;
    const int bid = blockIdx.x;
    const int n   = bid >> 7;
    const int h   = bid & 127;
    if (tid == 0) nfail = 0;

    const int c4 = tid & 31;
    const int g  = tid >> 5;
    const float4* xn = (const float4*)x + (size_t)n * C_IN * (PIX / 4)
                     + (size_t)h * (Ww / 4) + c4;
    float4 xv[4];
    #pragma unroll
    for (int k = 0; k < 4; ++k)
        xv[k] = xn[(size_t)(g + (k << 3)) * (PIX / 4)];

    float4* outn = (float4*)out + (size_t)n * O_OUT * (PIX / 4);
    const float4 z = make_float4(0.f, 0.f, 0.f, 0.f);
    #pragma unroll
    for (int j = 0; j < 8; ++j) {
        const int idx = (j << 8) + tid;
        const int o = idx >> 5, cc = idx & 31;
        outn[(size_t)o * (PIX / 4) + h * (Ww / 4) + cc] = z;
    }

    {
        const int o = tid >> 2, jj = tid & 3;
        float s = 0.f;
        #pragma unroll
        for (int c8 = 0; c8 < 8; ++c8) {
            const float* wp = w + (size_t)o * 576 + (jj * 8 + c8) * 9 + 3;
            s += fabsf(wp[0]) + fabsf(wp[1]) + fabsf(wp[2]);
        }
        s += __shfl_xor(s, 1); s += __shfl_xor(s, 2);
        float v = s + b[o];
        #pragma unroll
        for (int d = 4; d < 64; d <<= 1) v = fmaxf(v, __shfl_xor(v, d));
        if ((tid & 63) == 0) wmax[tid >> 6] = v;
    }
    {
        float4 a = make_float4(0.f, 0.f, 0.f, 0.f);
        #pragma unroll
        for (int k = 0; k < 4; ++k) {
            a.x += fabsf(xv[k].x); a.y += fabsf(xv[k].y);
            a.z += fabsf(xv[k].z); a.w += fabsf(xv[k].w);
        }
        *(float4*)&Ap[g * 128 + c4 * 4] = a;
    }
    __syncthreads();
    if (tid < 128) {
        float s = 0.f;
        #pragma unroll
        for (int gg = 0; gg < 8; ++gg) s += Ap[gg * 128 + tid];
        Afin[tid] = s;
    }
    __syncthreads();
    const float thr = fmaxf(fmaxf(wmax[0], wmax[1]),
                            fmaxf(wmax[2], wmax[3])) + 1.0f;
    if (tid < 128) {
        float S = Afin[tid];
        if (tid > 0)   S += Afin[tid - 1];
        if (tid < 127) S += Afin[tid + 1];
        if (!(S >= thr)) {
            u32 k = atomicAdd(&nfail, 1u);
            flist[k] = (u32)tid;
        }
    }
    __syncthreads();
    const u32 nf = nfail;
    if (nf) {
        const float* xs = x + (size_t)n * C_IN * PIX;
        for (u32 i = tid; i < nf * 64u; i += 256u) {
            const int col = (int)flist[i >> 6];
            const int o   = (int)(i & 63u);
            const float* wo = w + (size_t)o * C_IN * 9;
            float sum = 0.f;
            for (int c = 0; c < C_IN; ++c) {
                const float* xc = xs + (size_t)c * PIX;
                const float* wc = wo + c * 9;
                #pragma unroll
                for (int kh = 0; kh < 3; ++kh) {
                    const int gh = h + kh - 1;
                    #pragma unroll
                    for (int kw = 0; kw < 3; ++kw) {
                        const int gw = col + kw - 1;
                        const float xval = ((unsigned)gh < (unsigned)Hh &&
                                            (unsigned)gw < (unsigned)Ww)
                                           ? xc[gh * Ww + gw] : 0.f;
                        sum += fabsf(xval - wc[kh * 3 + kw]);
                    }
                }
            }
            out[(size_t)(n * O_OUT + o) * PIX + h * Ww + col] = fmaxf(b[o] - sum, 0.f);
        }
    }
}

extern "C" void kernel_launch(void* const* d_in, const int* in_sizes, int n_in,
                              void* d_out, int out_size, void* d_ws, size_t ws_size,
                              hipStream_t stream) {
    const float* x = (const float*)d_in[0];
    const float* w = (const float*)d_in[1];
    const float* b = (const float*)d_in[2];
    float* out = (float*)d_out;

    if (ws_size >= MASK_BYTES) {
        u64* mask = (u64*)d_ws;
        k1_fill_screen<<<2048, 256, 0, stream>>>(x, w, b, out, mask);
        k2_fixup<<<NB, 256, 0, stream>>>(x, w, b, out, mask);
    } else {
        adder_row_screen<<<NB * Hh, 256, 0, stream>>>(x, w, b, out);
    }
}

// Round 8
// 12.978 us; speedup vs baseline: 1.1909x; 1.1909x over previous
//
#include <hip/hip_runtime.h>

typedef unsigned int u32;

// AdderNet conv+ReLU: out[n,o,h,w] = relu(b[o] - sum_{c,kh,kw} |x - w|)
// x:[8,64,128,128] f32, w:[64,64,3,3], b:[64], out:[8,64,128,128] f32.
//
// Triangle-inequality screen over a SUBSET of terms (valid for all inputs):
//   sum_{all} |x_patch - w[o]| >= S'(n,h,w) - Wsum'[o]
// subset = channels 0..15, center input row (kh=1), in-bounds cols:
//   S'       = sum_{dc in {-1,0,1}, in-bounds} A16(n,h,w+dc)
//   A16      = sum_{c<16} |x[n,c,h,w]|
//   Wsum'[o] = sum_{c<16} sum_{kw} |w[o,c,1,kw]|
// If S' >= thr = max_o(Wsum'[o]+b[o]) + 1.0 (fp32 slack), all 64 outputs at
// that pixel are exactly 0. Failing cols are recomputed exactly (fp32), so
// the kernel is correct for arbitrary inputs; unit-scale margin ~5-7 sigma.
//
// KEY ORDERING LESSON (rounds 4-6): __syncthreads compiles to
// "s_waitcnt vmcnt(0); s_barrier" - any barrier AFTER the 32KB zero-store
// burst stalls the block on a full store round-trip. So: all barriers happen
// BEFORE any store is issued; the store burst goes LAST with no following
// barrier on the common path. The fix-up path (block-uniform if(nfail),
// normally never taken) inserts the store-draining barrier only when needed.
//
// 1024 blocks (n,h) x 256 threads; traffic = 33.5 MB write + 8.6 MB read.

#define Hh 128
#define Ww 128
#define C_IN 64
#define O_OUT 64
#define NB 8
#define PIX (Hh * Ww)

__global__ __launch_bounds__(256)
void adder_row_screen(const float* __restrict__ x, const float* __restrict__ w,
                      const float* __restrict__ b, float* __restrict__ out) {
    __shared__ float Ap[8 * 128];    // [g][col] partial A16
    __shared__ float Afin[128];      // A16 per col
    __shared__ float wmax[4];
    __shared__ u32   nfail;
    __shared__ u32   flist[128];

    const int tid = threadIdx.x;
    const int bid = blockIdx.x;
    const int n   = bid >> 7;        // image
    const int h   = bid & 127;       // row

    if (tid == 0) nfail = 0;

    // ---- 1) x loads first: 16 channels, thread -> (group g, float4-col c4) ----
    const int c4 = tid & 31;
    const int g  = tid >> 5;         // channels g and g+8
    const float4* xn = (const float4*)x + (size_t)n * C_IN * (PIX / 4)
                     + (size_t)h * (Ww / 4) + c4;
    const float4 a0 = xn[(size_t)g * (PIX / 4)];
    const float4 a1 = xn[(size_t)(g + 8) * (PIX / 4)];

    // ---- 2) w loads (L2-resident): thr = max_o( sum_{c<16}|w[o,c,1,:]| + b[o] ) ----
    {
        const int o = tid >> 2, jj = tid & 3;    // 64 o x 4 threads (4 ch each)
        float s = 0.f;
        #pragma unroll
        for (int k = 0; k < 4; ++k) {
            const float* wp = w + (size_t)o * 576 + (jj * 4 + k) * 9 + 3;  // kh=1
            s += fabsf(wp[0]) + fabsf(wp[1]) + fabsf(wp[2]);
        }
        s += __shfl_xor(s, 1); s += __shfl_xor(s, 2);
        float v = s + b[o];
        #pragma unroll
        for (int d = 4; d < 64; d <<= 1) v = fmaxf(v, __shfl_xor(v, d));
        if ((tid & 63) == 0) wmax[tid >> 6] = v;
    }

    // ---- 3) A16 partials -> LDS (no stores outstanding at any barrier) ----
    {
        float4 a;
        a.x = fabsf(a0.x) + fabsf(a1.x); a.y = fabsf(a0.y) + fabsf(a1.y);
        a.z = fabsf(a0.z) + fabsf(a1.z); a.w = fabsf(a0.w) + fabsf(a1.w);
        *(float4*)&Ap[g * 128 + c4 * 4] = a;
    }
    __syncthreads();

    if (tid < 128) {
        float s = 0.f;
        #pragma unroll
        for (int gg = 0; gg < 8; ++gg) s += Ap[gg * 128 + tid];
        Afin[tid] = s;
    }
    __syncthreads();

    const float thr = fmaxf(fmaxf(wmax[0], wmax[1]),
                            fmaxf(wmax[2], wmax[3])) + 1.0f;

    // ---- 4) screen (center-row taps, in-bounds cols) ----
    if (tid < 128) {
        float S = Afin[tid];
        if (tid > 0)   S += Afin[tid - 1];
        if (tid < 127) S += Afin[tid + 1];
        if (!(S >= thr)) {                       // cannot prove zero
            u32 k = atomicAdd(&nfail, 1u);
            flist[k] = (u32)tid;
        }
    }
    __syncthreads();   // publish nfail/flist (LDS only; no VMEM stores yet)
    const u32 nf = nfail;

    // ---- 5) zero-store burst LAST: 64 o-planes x row h = 2048 float4 ----
    // No barrier after this on the common path -> store latency never stalls us.
    float4* outn = (float4*)out + (size_t)n * O_OUT * (PIX / 4);
    const float4 z = make_float4(0.f, 0.f, 0.f, 0.f);
    #pragma unroll
    for (int j = 0; j < 8; ++j) {
        const int idx = (j << 8) + tid;          // 0..2047
        const int o = idx >> 5, cc = idx & 31;
        outn[(size_t)o * (PIX / 4) + h * (Ww / 4) + cc] = z;
    }

    // ---- 6) exact fp32 fix-up (block-uniform branch; normally never taken) ----
    if (nf) {
        __syncthreads();   // drains zero-stores so overwrites are ordered
        const float* xs = x + (size_t)n * C_IN * PIX;
        for (u32 i = tid; i < nf * 64u; i += 256u) {
            const int col = (int)flist[i >> 6];
            const int o   = (int)(i & 63u);
            const float* wo = w + (size_t)o * C_IN * 9;
            float sum = 0.f;
            for (int c = 0; c < C_IN; ++c) {
                const float* xc = xs + (size_t)c * PIX;
                const float* wc = wo + c * 9;
                #pragma unroll
                for (int kh = 0; kh < 3; ++kh) {
                    const int gh = h + kh - 1;
                    #pragma unroll
                    for (int kw = 0; kw < 3; ++kw) {
                        const int gw = col + kw - 1;
                        const float xval = ((unsigned)gh < (unsigned)Hh &&
                                            (unsigned)gw < (unsigned)Ww)
                                           ? xc[gh * Ww + gw] : 0.f;
                        sum += fabsf(xval - wc[kh * 3 + kw]);
                    }
                }
            }
            out[(size_t)(n * O_OUT + o) * PIX + h * Ww + col] = fmaxf(b[o] - sum, 0.f);
        }
    }
}

extern "C" void kernel_launch(void* const* d_in, const int* in_sizes, int n_in,
                              void* d_out, int out_size, void* d_ws, size_t ws_size,
                              hipStream_t stream) {
    const float* x = (const float*)d_in[0];
    const float* w = (const float*)d_in[1];
    const float* b = (const float*)d_in[2];
    float* out = (float*)d_out;

    adder_row_screen<<<NB * Hh, 256, 0, stream>>>(x, w, b, out);
}